// Round 3
// baseline (872.548 us; speedup 1.0000x reference)
//
#include <hip/hip_runtime.h>
#include <stdint.h>

// ---------------------------------------------------------------------------
// EvaLinearAttention on MI355X (gfx950).
// B=8, N=4096, C=768, H=12, D=64, npt=1. I/O fp32; GEMMs bf16 MFMA;
// attention middle (this round): simple fp32 vector implementation (bisect:
// round-2's MFMA attention passes are suspected of a fragment/swizzle bug).
// ---------------------------------------------------------------------------

typedef __attribute__((ext_vector_type(8))) short short8;
typedef __attribute__((ext_vector_type(4))) float floatx4;

__device__ __forceinline__ float b2f(unsigned short u) {
  union { unsigned int i; float f; } v; v.i = ((unsigned int)u) << 16; return v.f;
}
__device__ __forceinline__ unsigned short f2b(float f) {
  union { float f; unsigned int i; } v; v.f = f;
  unsigned int i = v.i;
  unsigned int r = (i + 0x7FFFu + ((i >> 16) & 1u)) >> 16;  // RNE
  return (unsigned short)r;
}
__device__ __forceinline__ void unpack2(unsigned int u, float& a, float& b) {
  union { unsigned int i; float f; } x, y;
  x.i = u << 16; y.i = u & 0xFFFF0000u;
  a = x.f; b = y.f;
}

__device__ __forceinline__ void stage16(const void* g, void* l) {
#if defined(__has_builtin) && __has_builtin(__builtin_amdgcn_global_load_lds)
  __builtin_amdgcn_global_load_lds(
      (const __attribute__((address_space(1))) unsigned int*)g,
      (__attribute__((address_space(3))) unsigned int*)l, 16, 0, 0);
#else
  *(uint4*)l = *(const uint4*)g;
#endif
}

// ---------------------------------------------------------------------------
__global__ __launch_bounds__(256) void f32_to_bf16(
    const float* __restrict__ in, unsigned short* __restrict__ out, int n) {
  const int i = (blockIdx.x * 256 + threadIdx.x) * 8;
  if (i + 7 < n) {
    float4 a = *(const float4*)(in + i);
    float4 b = *(const float4*)(in + i + 4);
    unsigned short tmp[8] = {f2b(a.x), f2b(a.y), f2b(a.z), f2b(a.w),
                             f2b(b.x), f2b(b.y), f2b(b.z), f2b(b.w)};
    *(uint4*)(out + i) = *(uint4*)tmp;
  }
}

// ---------------------------------------------------------------------------
// bf16 GEMM, B^T: Out[M,Nout] = A[M,K] * W[Nout,K]^T + bias. (m97 pattern)
// ---------------------------------------------------------------------------
template <int OUT_BF16>
__global__ __launch_bounds__(256) void gemm_bt(
    const unsigned short* __restrict__ A, const unsigned short* __restrict__ W,
    const float* __restrict__ bias, void* __restrict__ Out,
    int M, int K, int Nout) {
  __shared__ __align__(16) unsigned short sA[128 * 32];
  __shared__ __align__(16) unsigned short sB[128 * 32];
  const int bn = blockIdx.x, bm = blockIdx.y;
  const int t = threadIdx.x;
  const int lane = t & 63, wave = t >> 6;
  const int wm = (wave >> 1) * 64, wn = (wave & 1) * 64;
  const int lr = t >> 2;
  const int lc = (t & 3) * 8;
  const size_t baseA = (size_t)(bm * 128 + lr) * K + lc;
  const size_t baseB = (size_t)(bn * 128 + lr) * K + lc;
  floatx4 acc[4][4] = {};

  const int mr = lane & 15, kq = (lane >> 4) * 8;
  for (int k0 = 0; k0 < K; k0 += 32) {
    stage16(A + baseA + k0, &sA[t * 8]);
    stage16(A + baseA + (size_t)64 * K + k0, &sA[2048 + t * 8]);
    stage16(W + baseB + k0, &sB[t * 8]);
    stage16(W + baseB + (size_t)64 * K + k0, &sB[2048 + t * 8]);
    __syncthreads();
    short8 af[4], bfr[4];
#pragma unroll
    for (int i = 0; i < 4; i++) af[i] = *(const short8*)&sA[(wm + i * 16 + mr) * 32 + kq];
#pragma unroll
    for (int j = 0; j < 4; j++) bfr[j] = *(const short8*)&sB[(wn + j * 16 + mr) * 32 + kq];
#pragma unroll
    for (int i = 0; i < 4; i++)
#pragma unroll
      for (int j = 0; j < 4; j++)
        acc[i][j] = __builtin_amdgcn_mfma_f32_16x16x32_bf16(af[i], bfr[j], acc[i][j], 0, 0, 0);
    __syncthreads();
  }

  const int mr4 = (lane >> 4) * 4, nc = lane & 15;
#pragma unroll
  for (int j = 0; j < 4; j++) {
    const int gc = bn * 128 + wn + j * 16 + nc;
    const float bv = bias[gc];
#pragma unroll
    for (int i = 0; i < 4; i++) {
      const int gr0 = bm * 128 + wm + i * 16 + mr4;
#pragma unroll
      for (int r = 0; r < 4; r++) {
        float v = acc[i][j][r] + bv;
        if (OUT_BF16)
          ((unsigned short*)Out)[(size_t)(gr0 + r) * Nout + gc] = f2b(v);
        else
          ((float*)Out)[(size_t)(gr0 + r) * Nout + gc] = v;
      }
    }
  }
}

// ---------------------------------------------------------------------------
// pass_a (simple fp32): kvG[bh][e*64+d] = sum_n phi_k[n,d]*v[n,e];
//                       kvG[bh][4096+d] = sum_n phi_k[n,d]
// One block per (b,h). 32 tiles of 128 tokens. Threads t<128 compute phi_k
// (fp32, full 64-dim softmax in regs) + stage v (bf16 raw). All 4 waves
// then accumulate: wave w handles tokens [w*32,w*32+32) of the tile; lane
// owns d-block dg*4 (4 d) x e-block eg*16 (16 e). fp32 atomics at the end.
// ---------------------------------------------------------------------------
__global__ __launch_bounds__(256) void pass_a(
    const unsigned short* __restrict__ qkv, const float* __restrict__ rope,
    float* __restrict__ kvG) {
  __shared__ float sphi[128 * 65];               // 33,280 B (pad 65: no conflicts)
  __shared__ __align__(16) unsigned short sv[128 * 64];  // 16,384 B
  const int bh = blockIdx.x, b = bh / 12, h = bh % 12;
  const int t = threadIdx.x;
  const int lane = t & 63, wave = t >> 6;
  const int dg = lane >> 2;   // d = dg*4 + i
  const int eg = lane & 3;    // e = eg*16 + j
  float acc[4][16] = {};
  float ks4[4] = {};

  for (int tile = 0; tile < 32; tile++) {
    __syncthreads();
    if (t < 128) {
      const int n = tile * 128 + t;
      const size_t rowb = (size_t)(b * 4096 + n) * 2304;
      const unsigned short* kp = qkv + rowb + 768 + h * 64;
      float kk[64];
#pragma unroll
      for (int c = 0; c < 8; c++) {
        uint4 u = *(const uint4*)(kp + c * 8);
        unpack2(u.x, kk[c * 8 + 0], kk[c * 8 + 1]);
        unpack2(u.y, kk[c * 8 + 2], kk[c * 8 + 3]);
        unpack2(u.z, kk[c * 8 + 4], kk[c * 8 + 5]);
        unpack2(u.w, kk[c * 8 + 6], kk[c * 8 + 7]);
      }
      if (n > 0) {
        const float* rp = rope + (size_t)(n - 1) * 128;
#pragma unroll
        for (int c = 0; c < 8; c++) {
          float sn[8], cs[8];
          *(float4*)&sn[0] = *(const float4*)(rp + c * 8);
          *(float4*)&sn[4] = *(const float4*)(rp + c * 8 + 4);
          *(float4*)&cs[0] = *(const float4*)(rp + 64 + c * 8);
          *(float4*)&cs[4] = *(const float4*)(rp + 64 + c * 8 + 4);
#pragma unroll
          for (int i = 0; i < 4; i++) {
            float e = kk[c * 8 + 2 * i], o = kk[c * 8 + 2 * i + 1];
            kk[c * 8 + 2 * i] = e * cs[2 * i] - o * sn[2 * i];
            kk[c * 8 + 2 * i + 1] = o * cs[2 * i + 1] + e * sn[2 * i + 1];
          }
        }
      }
      float mx = kk[0];
#pragma unroll
      for (int i = 1; i < 64; i++) mx = fmaxf(mx, kk[i]);
      float s = 0.f;
#pragma unroll
      for (int i = 0; i < 64; i++) { float e = __expf(kk[i] - mx); kk[i] = e; s += e; }
      const float inv = 1.f / s;
#pragma unroll
      for (int d = 0; d < 64; d++) sphi[t * 65 + d] = kk[d] * inv;
      const unsigned short* vp = qkv + rowb + 1536 + h * 64;
#pragma unroll
      for (int c = 0; c < 8; c++)
        *(uint4*)&sv[t * 64 + c * 8] = *(const uint4*)(vp + c * 8);
    }
    __syncthreads();
    const int n0 = wave * 32;
    for (int nn = n0; nn < n0 + 32; nn++) {
      float p[4];
#pragma unroll
      for (int i = 0; i < 4; i++) p[i] = sphi[nn * 65 + dg * 4 + i];
#pragma unroll
      for (int i = 0; i < 4; i++) ks4[i] += p[i];
      float vv[16];
      {
        uint4 u0 = *(const uint4*)&sv[nn * 64 + eg * 16];
        uint4 u1 = *(const uint4*)&sv[nn * 64 + eg * 16 + 8];
        unpack2(u0.x, vv[0], vv[1]);   unpack2(u0.y, vv[2], vv[3]);
        unpack2(u0.z, vv[4], vv[5]);   unpack2(u0.w, vv[6], vv[7]);
        unpack2(u1.x, vv[8], vv[9]);   unpack2(u1.y, vv[10], vv[11]);
        unpack2(u1.z, vv[12], vv[13]); unpack2(u1.w, vv[14], vv[15]);
      }
#pragma unroll
      for (int i = 0; i < 4; i++)
#pragma unroll
        for (int j = 0; j < 16; j++)
          acc[i][j] += p[i] * vv[j];
    }
  }
  float* o = kvG + (size_t)bh * 4160;
#pragma unroll
  for (int i = 0; i < 4; i++)
#pragma unroll
    for (int j = 0; j < 16; j++)
      atomicAdd(&o[(eg * 16 + j) * 64 + dg * 4 + i], acc[i][j]);
  if (eg == 0) {
#pragma unroll
    for (int i = 0; i < 4; i++) atomicAdd(&o[4096 + dg * 4 + i], ks4[i]);
  }
}

// ---------------------------------------------------------------------------
// pass_b (simple): one thread per token. phi_q fp32 in regs; kv staged to
// LDS as bf16 [e][d]; out[n,e] = (sum_d phi_q[d]*kv[d,e]) / (z+eps), bf16.
// All lanes read the same LDS address (broadcast, conflict-free).
// ---------------------------------------------------------------------------
__global__ __launch_bounds__(256) void pass_b(
    const unsigned short* __restrict__ qkv, const float* __restrict__ rope,
    const float* __restrict__ kvG, unsigned short* __restrict__ attn) {
  __shared__ __align__(16) unsigned short skvh[4096];  // [e][d] bf16
  __shared__ float sks[64];
  const int bh = blockIdx.x, b = bh / 12, h = bh % 12;
  const int t = threadIdx.x;
  const float* kvb = kvG + (size_t)bh * 4160;
  {
    const float* src = kvb + t * 16;
    unsigned short tmp[16];
#pragma unroll
    for (int i = 0; i < 16; i++) tmp[i] = f2b(src[i]);
    *(uint4*)&skvh[t * 16] = *(uint4*)&tmp[0];
    *(uint4*)&skvh[t * 16 + 8] = *(uint4*)&tmp[8];
  }
  if (t < 64) sks[t] = kvb[4096 + t];
  __syncthreads();

  const int n = blockIdx.y * 256 + t;
  const size_t rowb = (size_t)(b * 4096 + n) * 2304;
  const unsigned short* qp = qkv + rowb + h * 64;
  float ph[64];
#pragma unroll
  for (int c = 0; c < 8; c++) {
    uint4 u = *(const uint4*)(qp + c * 8);
    unpack2(u.x, ph[c * 8 + 0], ph[c * 8 + 1]);
    unpack2(u.y, ph[c * 8 + 2], ph[c * 8 + 3]);
    unpack2(u.z, ph[c * 8 + 4], ph[c * 8 + 5]);
    unpack2(u.w, ph[c * 8 + 6], ph[c * 8 + 7]);
  }
  if (n > 0) {
    const float* rp = rope + (size_t)(n - 1) * 128;
#pragma unroll
    for (int c = 0; c < 8; c++) {
      float sn[8], cs[8];
      *(float4*)&sn[0] = *(const float4*)(rp + c * 8);
      *(float4*)&sn[4] = *(const float4*)(rp + c * 8 + 4);
      *(float4*)&cs[0] = *(const float4*)(rp + 64 + c * 8);
      *(float4*)&cs[4] = *(const float4*)(rp + 64 + c * 8 + 4);
#pragma unroll
      for (int i = 0; i < 4; i++) {
        float e = ph[c * 8 + 2 * i], o = ph[c * 8 + 2 * i + 1];
        ph[c * 8 + 2 * i] = e * cs[2 * i] - o * sn[2 * i];
        ph[c * 8 + 2 * i + 1] = o * cs[2 * i + 1] + e * sn[2 * i + 1];
      }
    }
  }
  float mx = ph[0];
#pragma unroll
  for (int i = 1; i < 64; i++) mx = fmaxf(mx, ph[i]);
  float s = 0.f;
#pragma unroll
  for (int i = 0; i < 64; i++) { float e = __expf(ph[i] - mx); ph[i] = e; s += e; }
  const float inv = 1.f / s;
  float z = 0.f;
#pragma unroll
  for (int i = 0; i < 64; i++) { ph[i] *= inv; z += ph[i] * sks[i]; }
  const float zi = 1.f / (z + 1e-5f);

  unsigned short* orow = attn + (size_t)(b * 4096 + n) * 768 + h * 64;
  unsigned short tmp8[8];
  for (int e = 0; e < 64; e++) {
    float acc = 0.f;
#pragma unroll
    for (int c = 0; c < 8; c++) {
      uint4 u = *(const uint4*)&skvh[e * 64 + c * 8];
      float f0, f1;
      unpack2(u.x, f0, f1); acc += ph[c * 8 + 0] * f0 + ph[c * 8 + 1] * f1;
      unpack2(u.y, f0, f1); acc += ph[c * 8 + 2] * f0 + ph[c * 8 + 3] * f1;
      unpack2(u.z, f0, f1); acc += ph[c * 8 + 4] * f0 + ph[c * 8 + 5] * f1;
      unpack2(u.w, f0, f1); acc += ph[c * 8 + 6] * f0 + ph[c * 8 + 7] * f1;
    }
    tmp8[e & 7] = f2b(acc * zi);
    if ((e & 7) == 7) *(uint4*)&orow[e - 7] = *(uint4*)&tmp8[0];
  }
}

// ---------------------------------------------------------------------------
// LayerNorm over C=768, in-place on bf16 buffer; gamma/beta fp32.
// ---------------------------------------------------------------------------
__global__ __launch_bounds__(256) void ln_kernel(
    unsigned short* __restrict__ buf, const float* __restrict__ g,
    const float* __restrict__ be) {
  const int row = blockIdx.x;
  const int t = threadIdx.x;
  unsigned short* p = buf + (size_t)row * 768;
  const float x0 = b2f(p[t]), x1 = b2f(p[t + 256]), x2 = b2f(p[t + 512]);
  float s = x0 + x1 + x2;
  float ss = x0 * x0 + x1 * x1 + x2 * x2;
#pragma unroll
  for (int m = 1; m < 64; m <<= 1) { s += __shfl_xor(s, m); ss += __shfl_xor(ss, m); }
  __shared__ float red[8];
  const int wave = t >> 6, lane = t & 63;
  if (lane == 0) { red[wave] = s; red[4 + wave] = ss; }
  __syncthreads();
  s = red[0] + red[1] + red[2] + red[3];
  ss = red[4] + red[5] + red[6] + red[7];
  const float mean = s * (1.f / 768.f);
  const float var = ss * (1.f / 768.f) - mean * mean;
  const float rsq = rsqrtf(var + 1e-5f);
  p[t] = f2b((x0 - mean) * rsq * g[t] + be[t]);
  p[t + 256] = f2b((x1 - mean) * rsq * g[t + 256] + be[t + 256]);
  p[t + 512] = f2b((x2 - mean) * rsq * g[t + 512] + be[t + 512]);
}

__global__ void setup_bias(const float* qb, const float* vb, const float* pb,
                           float* qkvb, float* projb) {
  const int i = blockIdx.x * 256 + threadIdx.x;
  if (i < 2304) qkvb[i] = (i < 768) ? qb[i] : (i >= 1536 ? vb[i - 1536] : 0.f);
  if (i < 768) projb[i] = pb[i];
}

// ---------------------------------------------------------------------------
extern "C" void kernel_launch(void* const* d_in, const int* in_sizes, int n_in,
                              void* d_out, int out_size, void* d_ws, size_t ws_size,
                              hipStream_t stream) {
  (void)in_sizes; (void)n_in; (void)out_size; (void)ws_size;
  const float* x      = (const float*)d_in[0];
  const float* rope   = (const float*)d_in[1];
  const float* qkv_w  = (const float*)d_in[2];
  const float* q_bias = (const float*)d_in[3];
  const float* v_bias = (const float*)d_in[4];
  const float* norm_g = (const float*)d_in[5];
  const float* norm_b = (const float*)d_in[6];
  const float* proj_w = (const float*)d_in[7];
  const float* proj_b = (const float*)d_in[8];

  char* ws = (char*)d_ws;
  unsigned short* qkv  = (unsigned short*)ws;                // 150,994,944 B
  unsigned short* attn = (unsigned short*)(ws + 150994944);  //  50,331,648 B
  unsigned short* xbf  = attn;  // aliased: x_bf16 dead before attn is written
  float* kvG   = (float*)(ws + 201326592);                   //   1,597,440 B
  float* qkvb  = (float*)(ws + 202924032);
  float* projb = (float*)(ws + 202933248);
  unsigned short* wbf  = (unsigned short*)(ws + 202936320);  //   3,538,944 B
  unsigned short* pwbf = (unsigned short*)(ws + 206475264);  //   1,179,648 B

  f32_to_bf16<<<dim3(12288), dim3(256), 0, stream>>>(x, xbf, 25165824);
  f32_to_bf16<<<dim3(864), dim3(256), 0, stream>>>(qkv_w, wbf, 1769472);
  f32_to_bf16<<<dim3(288), dim3(256), 0, stream>>>(proj_w, pwbf, 589824);
  hipMemsetAsync(kvG, 0, 96 * 4160 * sizeof(float), stream);
  setup_bias<<<dim3(9), dim3(256), 0, stream>>>(q_bias, v_bias, proj_b, qkvb, projb);
  // qkv = x @ qkv_w^T + qkv_bias (M=32768, K=768, Nout=2304), bf16 out
  gemm_bt<1><<<dim3(18, 256), dim3(256), 0, stream>>>(xbf, wbf, qkvb, qkv, 32768, 768, 2304);
  // kv / ksum reduction (simple fp32)
  pass_a<<<dim3(96), dim3(256), 0, stream>>>(qkv, rope, kvG);
  // attn = phi_q @ kv / (z + eps) (simple fp32 -> bf16)
  pass_b<<<dim3(96, 16), dim3(256), 0, stream>>>(qkv, rope, kvG, attn);
  // LayerNorm in-place
  ln_kernel<<<dim3(32768), dim3(256), 0, stream>>>(attn, norm_g, norm_b);
  // out = ln @ proj_w^T + proj_b (M=32768, K=768, Nout=768) -> d_out fp32
  gemm_bt<0><<<dim3(6, 256), dim3(256), 0, stream>>>(attn, pwbf, projb, d_out, 32768, 768, 768);
}